// Round 1
// baseline (412.594 us; speedup 1.0000x reference)
//
#include <hip/hip_runtime.h>
#include <stdint.h>

typedef unsigned short u16;
typedef __attribute__((ext_vector_type(4))) float f32x4;
typedef __attribute__((ext_vector_type(8))) __bf16 bf16x8;
typedef __attribute__((ext_vector_type(8))) u16 u16x8;
typedef __attribute__((ext_vector_type(4))) u16 u16x4;

// round-to-nearest-even f32 -> bf16
__device__ __forceinline__ u16 f2bf(float f) {
  union { float f; uint32_t u; } v; v.f = f;
  uint32_t u = v.u;
  u = u + 0x7FFFu + ((u >> 16) & 1u);
  return (u16)(u >> 16);
}

// async global->LDS, 16B per lane. LDS dest must be wave-uniform (HW adds lane*16).
__device__ __forceinline__ void gload_lds16(const u16* g, u16* l) {
  u16* gg = const_cast<u16*>(g);
  __builtin_amdgcn_global_load_lds(
      (__attribute__((address_space(1))) void*)gg,
      (__attribute__((address_space(3))) void*)l, 16, 0, 0);
}

// ---------------- prep: x (f32) -> bf16 ----------------
__global__ __launch_bounds__(256) void k_cvt_bf16(const float* __restrict__ in,
                                                  u16* __restrict__ out, int n8) {
  int i = blockIdx.x * 256 + threadIdx.x;
  if (i >= n8) return;
  const float4* p = (const float4*)in;
  float4 a = p[(size_t)2 * i];
  float4 b = p[(size_t)2 * i + 1];
  u16x8 r;
  r[0] = f2bf(a.x); r[1] = f2bf(a.y); r[2] = f2bf(a.z); r[3] = f2bf(a.w);
  r[4] = f2bf(b.x); r[5] = f2bf(b.y); r[6] = f2bf(b.z); r[7] = f2bf(b.w);
  *(u16x8*)(out + ((size_t)i << 3)) = r;
}

// ---------------- prep: W' = W + 4 * B @ A, cast to bf16 ----------------
// N=4096, K=4096, R=4 hardcoded. One thread per 4 consecutive i of one o.
__global__ __launch_bounds__(256) void k_fold_w(const float* __restrict__ W,
                                                const float* __restrict__ Am,
                                                const float* __restrict__ Bm,
                                                u16* __restrict__ out) {
  int t = blockIdx.x * 256 + threadIdx.x;      // t in [0, 4096*1024)
  int o = t >> 10;
  int i = (t & 1023) << 2;
  const float4 w  = *(const float4*)(W + ((size_t)o << 12) + i);
  const float4 b  = *(const float4*)(Bm + (o << 2));
  const float4 a0 = *(const float4*)(Am + i);
  const float4 a1 = *(const float4*)(Am + 4096 + i);
  const float4 a2 = *(const float4*)(Am + 8192 + i);
  const float4 a3 = *(const float4*)(Am + 12288 + i);
  u16x4 r;
  r[0] = f2bf(w.x + 4.f * (b.x * a0.x + b.y * a1.x + b.z * a2.x + b.w * a3.x));
  r[1] = f2bf(w.y + 4.f * (b.x * a0.y + b.y * a1.y + b.z * a2.y + b.w * a3.y));
  r[2] = f2bf(w.z + 4.f * (b.x * a0.z + b.y * a1.z + b.z * a2.z + b.w * a3.z));
  r[3] = f2bf(w.w + 4.f * (b.x * a0.w + b.y * a1.w + b.z * a2.w + b.w * a3.w));
  *(u16x4*)(out + ((size_t)t << 2)) = r;
}

// ---------------- main bf16 GEMM, B^T layout ----------------
// C[M][N] = A[M][K] * B[N][K]^T.  128x128 tile, BK=32, 4 waves (2x2), each wave 64x64.
// m97 structure: global_load_lds(16B) staging, 2 barriers/K-step, 16x16x32 MFMA.
__global__ __launch_bounds__(256) void k_gemm_bf16(const u16* __restrict__ Ag,
                                                   const u16* __restrict__ Bg,
                                                   float* __restrict__ C,
                                                   int M, int N, int K) {
  __shared__ __attribute__((aligned(16))) u16 As[128 * 32];
  __shared__ __attribute__((aligned(16))) u16 Bs[128 * 32];
  const int tid  = threadIdx.x;
  const int wave = tid >> 6;
  const int lane = tid & 63;
  const int wr = wave >> 1;      // 2x2 wave grid over the 128x128 tile
  const int wc = wave & 1;
  const int m0 = blockIdx.y * 128;
  const int n0 = blockIdx.x * 128;

  // staging: tile = 512 chunks of 16B; chunk c -> row c/4, k-offset (c%4)*8
  const int c0 = (wave << 6) + lane;       // chunks 0..255
  const int c1 = 256 + c0;                 // chunks 256..511
  const u16* gA0 = Ag + (size_t)(m0 + (c0 >> 2)) * K + ((c0 & 3) << 3);
  const u16* gA1 = Ag + (size_t)(m0 + (c1 >> 2)) * K + ((c1 & 3) << 3);
  const u16* gB0 = Bg + (size_t)(n0 + (c0 >> 2)) * K + ((c0 & 3) << 3);
  const u16* gB1 = Bg + (size_t)(n0 + (c1 >> 2)) * K + ((c1 & 3) << 3);
  u16* lA0 = As + (wave << 9);             // wave-uniform LDS bases (1KB apart)
  u16* lA1 = As + 2048 + (wave << 9);
  u16* lB0 = Bs + (wave << 9);
  u16* lB1 = Bs + 2048 + (wave << 9);

  f32x4 acc[4][4] = {};

  // fragment read base: row = w*64 + f*16 + (lane&15), k = (lane>>4)*8
  const int aoff = (((wr << 6) + (lane & 15)) << 5) + ((lane >> 4) << 3);
  const int boff = (((wc << 6) + (lane & 15)) << 5) + ((lane >> 4) << 3);

  for (int kt = 0; kt < K; kt += 32) {
    __syncthreads();                 // previous compute done before overwrite
    gload_lds16(gA0 + kt, lA0);
    gload_lds16(gA1 + kt, lA1);
    gload_lds16(gB0 + kt, lB0);
    gload_lds16(gB1 + kt, lB1);
    __syncthreads();                 // compiler drains vmcnt(0) before barrier

    bf16x8 a[4], b[4];
#pragma unroll
    for (int f = 0; f < 4; ++f) {
      a[f] = *(const bf16x8*)(As + aoff + (f << 9));   // f*16 rows * 32 elems
      b[f] = *(const bf16x8*)(Bs + boff + (f << 9));
    }
#pragma unroll
    for (int i = 0; i < 4; ++i)
#pragma unroll
      for (int j = 0; j < 4; ++j)
        acc[i][j] = __builtin_amdgcn_mfma_f32_16x16x32_bf16(a[i], b[j], acc[i][j], 0, 0, 0);
  }

  // C/D layout (m89-verified): col = lane&15, row = (lane>>4)*4 + reg
  const int crow = m0 + (wr << 6) + ((lane >> 4) << 2);
  const int ccol = n0 + (wc << 6) + (lane & 15);
#pragma unroll
  for (int i = 0; i < 4; ++i)
#pragma unroll
    for (int j = 0; j < 4; ++j)
#pragma unroll
      for (int v = 0; v < 4; ++v)
        C[(size_t)(crow + (i << 4) + v) * N + ccol + (j << 4)] = acc[i][j][v];
}

// ---------------- fallback (no workspace): fp32 tiled GEMM with on-the-fly fold ----
__global__ __launch_bounds__(256) void k_fallback(const float* __restrict__ X,
                                                  const float* __restrict__ W,
                                                  const float* __restrict__ Am,
                                                  const float* __restrict__ Bm,
                                                  float* __restrict__ C,
                                                  int M, int N, int K) {
  __shared__ float Xs[64][16];
  __shared__ float Ws[64][17];
  const int tid = threadIdx.x;
  const int tn = tid & 15, tm = tid >> 4;
  const int m0 = blockIdx.y * 64, n0 = blockIdx.x * 64;
  float acc[4][4] = {};
  for (int kt = 0; kt < K; kt += 16) {
    __syncthreads();
#pragma unroll
    for (int q = 0; q < 4; ++q) {
      int idx = q * 256 + tid;
      int r = idx >> 4, c = idx & 15;
      Xs[r][c] = X[(size_t)(m0 + r) * K + kt + c];
      float w = W[(size_t)(n0 + r) * K + kt + c];
      float4 b = *(const float4*)(Bm + ((n0 + r) << 2));
      w += 4.f * (b.x * Am[kt + c] + b.y * Am[4096 + kt + c] +
                  b.z * Am[8192 + kt + c] + b.w * Am[12288 + kt + c]);
      Ws[r][c] = w;
    }
    __syncthreads();
#pragma unroll
    for (int k = 0; k < 16; ++k) {
      float xv[4], wv[4];
#pragma unroll
      for (int i = 0; i < 4; ++i) xv[i] = Xs[tm * 4 + i][k];
#pragma unroll
      for (int j = 0; j < 4; ++j) wv[j] = Ws[tn * 4 + j][k];
#pragma unroll
      for (int i = 0; i < 4; ++i)
#pragma unroll
        for (int j = 0; j < 4; ++j) acc[i][j] += xv[i] * wv[j];
    }
  }
#pragma unroll
  for (int i = 0; i < 4; ++i)
#pragma unroll
    for (int j = 0; j < 4; ++j)
      C[(size_t)(m0 + tm * 4 + i) * N + n0 + tn * 4 + j] = acc[i][j];
}

extern "C" void kernel_launch(void* const* d_in, const int* in_sizes, int n_in,
                              void* d_out, int out_size, void* d_ws, size_t ws_size,
                              hipStream_t stream) {
  const float* x  = (const float*)d_in[0];
  const float* W  = (const float*)d_in[1];
  const float* lA = (const float*)d_in[2];
  const float* lB = (const float*)d_in[3];
  float* out = (float*)d_out;
  const int K = 4096, N = 4096;
  const int M = in_sizes[0] / K;   // 8192
  const size_t need = ((size_t)M + (size_t)N) * (size_t)K * sizeof(u16);

  if (ws_size >= need && (M % 128) == 0) {
    u16* xb = (u16*)d_ws;
    u16* wb = xb + (size_t)M * K;
    const int n8 = M * (K / 8);
    k_cvt_bf16<<<dim3((n8 + 255) / 256), dim3(256), 0, stream>>>(x, xb, n8);
    const int tw = N * (K / 4);
    k_fold_w<<<dim3(tw / 256), dim3(256), 0, stream>>>(W, lA, lB, wb);
    k_gemm_bf16<<<dim3(N / 128, M / 128), dim3(256), 0, stream>>>(xb, wb, out, M, N, K);
  } else {
    k_fallback<<<dim3(N / 64, M / 64), dim3(256), 0, stream>>>(x, W, lA, lB, out, M, N, K);
  }
}

// Round 2
// 310.272 us; speedup vs baseline: 1.3298x; 1.3298x over previous
//
#include <hip/hip_runtime.h>
#include <stdint.h>

typedef unsigned short u16;
typedef __attribute__((ext_vector_type(4))) float f32x4;
typedef __attribute__((ext_vector_type(8))) __bf16 bf16x8;
typedef __attribute__((ext_vector_type(8))) u16 u16x8;
typedef __attribute__((ext_vector_type(4))) u16 u16x4;

// round-to-nearest-even f32 -> bf16
__device__ __forceinline__ u16 f2bf(float f) {
  union { float f; uint32_t u; } v; v.f = f;
  uint32_t u = v.u;
  u = u + 0x7FFFu + ((u >> 16) & 1u);
  return (u16)(u >> 16);
}

// async global->LDS, 16B per lane. LDS dest wave-uniform base + lane*16.
__device__ __forceinline__ void gload_lds16(const u16* g, u16* l) {
  u16* gg = const_cast<u16*>(g);
  __builtin_amdgcn_global_load_lds(
      (__attribute__((address_space(1))) void*)gg,
      (__attribute__((address_space(3))) void*)l, 16, 0, 0);
}

// ---------------- prep: x (f32) -> bf16 ----------------
__global__ __launch_bounds__(256) void k_cvt_bf16(const float* __restrict__ in,
                                                  u16* __restrict__ out, int n8) {
  int i = blockIdx.x * 256 + threadIdx.x;
  if (i >= n8) return;
  const float4* p = (const float4*)in;
  float4 a = p[(size_t)2 * i];
  float4 b = p[(size_t)2 * i + 1];
  u16x8 r;
  r[0] = f2bf(a.x); r[1] = f2bf(a.y); r[2] = f2bf(a.z); r[3] = f2bf(a.w);
  r[4] = f2bf(b.x); r[5] = f2bf(b.y); r[6] = f2bf(b.z); r[7] = f2bf(b.w);
  *(u16x8*)(out + ((size_t)i << 3)) = r;
}

// ---------------- prep: W' = W + 4 * B @ A, cast to bf16 ----------------
__global__ __launch_bounds__(256) void k_fold_w(const float* __restrict__ W,
                                                const float* __restrict__ Am,
                                                const float* __restrict__ Bm,
                                                u16* __restrict__ out) {
  int t = blockIdx.x * 256 + threadIdx.x;      // t in [0, 4096*1024)
  int o = t >> 10;
  int i = (t & 1023) << 2;
  const float4 w  = *(const float4*)(W + ((size_t)o << 12) + i);
  const float4 b  = *(const float4*)(Bm + (o << 2));
  const float4 a0 = *(const float4*)(Am + i);
  const float4 a1 = *(const float4*)(Am + 4096 + i);
  const float4 a2 = *(const float4*)(Am + 8192 + i);
  const float4 a3 = *(const float4*)(Am + 12288 + i);
  u16x4 r;
  r[0] = f2bf(w.x + 4.f * (b.x * a0.x + b.y * a1.x + b.z * a2.x + b.w * a3.x));
  r[1] = f2bf(w.y + 4.f * (b.x * a0.y + b.y * a1.y + b.z * a2.y + b.w * a3.y));
  r[2] = f2bf(w.z + 4.f * (b.x * a0.z + b.y * a1.z + b.z * a2.z + b.w * a3.z));
  r[3] = f2bf(w.w + 4.f * (b.x * a0.w + b.y * a1.w + b.z * a2.w + b.w * a3.w));
  *(u16x4*)(out + ((size_t)t << 2)) = r;
}

// ================= deep-pipelined 256x256 GEMM, C = A * B^T =================
// A[M][K], B[N][K] bf16, C[M][N] f32.  Tile 256x256, BK=32, ring of 4 LDS
// buffers (128 KiB), 8 waves (2Mx4N), per-wave 128x64 out, 2 phases/K-tile.
// T2: reads XOR-swizzled (c ^= (row>>1)&3 on 16B chunks), sources pre-swizzled
// so global_load_lds' linear dest yields the swizzled layout (rule #21).
// T4: counted vmcnt(8) once per tile (2 tiles in flight), never 0 in loop.
// T5: setprio around each 16-MFMA cluster.
__global__ __launch_bounds__(512, 2) void k_gemm8p(const u16* __restrict__ Ag,
                                                   const u16* __restrict__ Bg,
                                                   float* __restrict__ C,
                                                   int M, int N, int K) {
  __shared__ __attribute__((aligned(16))) u16 As[4 * 8192];
  __shared__ __attribute__((aligned(16))) u16 Bs[4 * 8192];
  const int tid  = threadIdx.x;
  const int wave = tid >> 6, lane = tid & 63;
  const int wr = wave >> 2, wc = wave & 3;   // 2 x 4 wave grid
  const int m0 = blockIdx.y * 256, n0 = blockIdx.x * 256;
  const int NT = K >> 5;                     // number of 32-deep K tiles (>=4)

  // staging: 1024 chunks/tile/operand; thread owns chunks tid and tid+512.
  // chunk c -> row c>>2, LDS slot c&3; source k-chunk = (c&3) ^ ((c>>3)&3)
  const int srow = tid >> 2;
  const int csrc = (tid & 3) ^ ((tid >> 3) & 3);
  const u16* gA0 = Ag + (size_t)(m0 + srow) * K + csrc * 8;
  const u16* gA1 = gA0 + (size_t)128 * K;
  const u16* gB0 = Bg + (size_t)(n0 + srow) * K + csrc * 8;
  const u16* gB1 = gB0 + (size_t)128 * K;
  const int l0 = wave << 9;                  // wave-uniform LDS bases (elems)
  const int l1 = 4096 + (wave << 9);

  // fragment reads: row = base + (lane&15), k-chunk swizzled per lane
  const int l4 = lane & 15;
  const int ke = (((lane >> 4) ^ ((lane >> 1) & 3)) << 3);  // elem offset
  const int arow = (wr << 7) + l4;
  const int brow = (wc << 6) + l4;

  f32x4 acc[8][4] = {};

  // prologue: stage tiles 0..2 (12 loads), keep newest 8 in flight
  for (int t = 0; t < 3; ++t) {
    const int kt = t << 5;
    u16* sa = As + (t << 13);
    u16* sb = Bs + (t << 13);
    gload_lds16(gA0 + kt, sa + l0);
    gload_lds16(gA1 + kt, sa + l1);
    gload_lds16(gB0 + kt, sb + l0);
    gload_lds16(gB1 + kt, sb + l1);
  }
  asm volatile("s_waitcnt vmcnt(8)" ::: "memory");   // tile 0 landed
  __builtin_amdgcn_s_barrier();

  for (int t = 0; t < NT; ++t) {
    const u16* a_ = As + ((t & 3) << 13);
    const u16* b_ = Bs + ((t & 3) << 13);
    const bool stage = (t + 3) < NT;
    const int kt3 = (t + 3) << 5;
    u16* sa = As + (((t + 3) & 3) << 13);
    u16* sb = Bs + (((t + 3) & 3) << 13);

    // ---- phase 0 (rows wr*128 + [0,64)) ----
    bf16x8 af[4], bq[4];
#pragma unroll
    for (int f = 0; f < 4; ++f)
      af[f] = *(const bf16x8*)(a_ + (arow + f * 16) * 32 + ke);
#pragma unroll
    for (int f = 0; f < 4; ++f)
      bq[f] = *(const bf16x8*)(b_ + (brow + f * 16) * 32 + ke);
    if (stage) {                      // A half of tile t+3 (buffer last read at t-1)
      gload_lds16(gA0 + kt3, sa + l0);
      gload_lds16(gA1 + kt3, sa + l1);
    }
    __builtin_amdgcn_s_barrier();
    __builtin_amdgcn_s_setprio(1);
#pragma unroll
    for (int f = 0; f < 4; ++f)
#pragma unroll
      for (int j = 0; j < 4; ++j)
        acc[f][j] = __builtin_amdgcn_mfma_f32_16x16x32_bf16(af[f], bq[j], acc[f][j], 0, 0, 0);
    __builtin_amdgcn_s_setprio(0);
    __builtin_amdgcn_s_barrier();

    // ---- phase 1 (rows wr*128 + [64,128)) ----
#pragma unroll
    for (int f = 0; f < 4; ++f)
      af[f] = *(const bf16x8*)(a_ + (arow + 64 + f * 16) * 32 + ke);
    if (stage) {                      // B half of tile t+3
      gload_lds16(gB0 + kt3, sb + l0);
      gload_lds16(gB1 + kt3, sb + l1);
    }
    __builtin_amdgcn_s_barrier();
    __builtin_amdgcn_s_setprio(1);
#pragma unroll
    for (int f = 0; f < 4; ++f)
#pragma unroll
      for (int j = 0; j < 4; ++j)
        acc[4 + f][j] = __builtin_amdgcn_mfma_f32_16x16x32_bf16(af[f], bq[j], acc[4 + f][j], 0, 0, 0);
    __builtin_amdgcn_s_setprio(0);
    // counted wait: guarantee tile t+1 landed before next iteration's reads.
    if (t + 4 <= NT)      { asm volatile("s_waitcnt vmcnt(8)" ::: "memory"); }
    else if (t + 3 <= NT) { asm volatile("s_waitcnt vmcnt(4)" ::: "memory"); }
    else if (t + 2 <= NT) { asm volatile("s_waitcnt vmcnt(0)" ::: "memory"); }
    __builtin_amdgcn_s_barrier();
  }

  // epilogue: C/D layout col = lane&15, row = (lane>>4)*4 + reg (m89-verified)
  const int crow = m0 + (wr << 7) + ((lane >> 4) << 2);
  const int ccol = n0 + (wc << 6) + l4;
#pragma unroll
  for (int i = 0; i < 8; ++i)
#pragma unroll
    for (int j = 0; j < 4; ++j)
#pragma unroll
      for (int v = 0; v < 4; ++v)
        C[(size_t)(crow + i * 16 + v) * N + ccol + j * 16] = acc[i][j][v];
}

// ---------------- 128x128 m97-structure GEMM (backup path) ----------------
__global__ __launch_bounds__(256) void k_gemm_bf16(const u16* __restrict__ Ag,
                                                   const u16* __restrict__ Bg,
                                                   float* __restrict__ C,
                                                   int M, int N, int K) {
  __shared__ __attribute__((aligned(16))) u16 As[128 * 32];
  __shared__ __attribute__((aligned(16))) u16 Bs[128 * 32];
  const int tid  = threadIdx.x;
  const int wave = tid >> 6;
  const int lane = tid & 63;
  const int wr = wave >> 1;
  const int wc = wave & 1;
  const int m0 = blockIdx.y * 128;
  const int n0 = blockIdx.x * 128;
  const int c0 = (wave << 6) + lane;
  const int c1 = 256 + c0;
  const u16* gA0 = Ag + (size_t)(m0 + (c0 >> 2)) * K + ((c0 & 3) << 3);
  const u16* gA1 = Ag + (size_t)(m0 + (c1 >> 2)) * K + ((c1 & 3) << 3);
  const u16* gB0 = Bg + (size_t)(n0 + (c0 >> 2)) * K + ((c0 & 3) << 3);
  const u16* gB1 = Bg + (size_t)(n0 + (c1 >> 2)) * K + ((c1 & 3) << 3);
  u16* lA0 = As + (wave << 9);
  u16* lA1 = As + 2048 + (wave << 9);
  u16* lB0 = Bs + (wave << 9);
  u16* lB1 = Bs + 2048 + (wave << 9);
  f32x4 acc[4][4] = {};
  const int aoff = (((wr << 6) + (lane & 15)) << 5) + ((lane >> 4) << 3);
  const int boff = (((wc << 6) + (lane & 15)) << 5) + ((lane >> 4) << 3);
  for (int kt = 0; kt < K; kt += 32) {
    __syncthreads();
    gload_lds16(gA0 + kt, lA0);
    gload_lds16(gA1 + kt, lA1);
    gload_lds16(gB0 + kt, lB0);
    gload_lds16(gB1 + kt, lB1);
    __syncthreads();
    bf16x8 a[4], b[4];
#pragma unroll
    for (int f = 0; f < 4; ++f) {
      a[f] = *(const bf16x8*)(As + aoff + (f << 9));
      b[f] = *(const bf16x8*)(Bs + boff + (f << 9));
    }
#pragma unroll
    for (int i = 0; i < 4; ++i)
#pragma unroll
      for (int j = 0; j < 4; ++j)
        acc[i][j] = __builtin_amdgcn_mfma_f32_16x16x32_bf16(a[i], b[j], acc[i][j], 0, 0, 0);
  }
  const int crow = m0 + (wr << 6) + ((lane >> 4) << 2);
  const int ccol = n0 + (wc << 6) + (lane & 15);
#pragma unroll
  for (int i = 0; i < 4; ++i)
#pragma unroll
    for (int j = 0; j < 4; ++j)
#pragma unroll
      for (int v = 0; v < 4; ++v)
        C[(size_t)(crow + (i << 4) + v) * N + ccol + (j << 4)] = acc[i][j][v];
}

// ---------------- fallback (no workspace): fp32 tiled GEMM ----------------
__global__ __launch_bounds__(256) void k_fallback(const float* __restrict__ X,
                                                  const float* __restrict__ W,
                                                  const float* __restrict__ Am,
                                                  const float* __restrict__ Bm,
                                                  float* __restrict__ C,
                                                  int M, int N, int K) {
  __shared__ float Xs[64][16];
  __shared__ float Ws[64][17];
  const int tid = threadIdx.x;
  const int tn = tid & 15, tm = tid >> 4;
  const int m0 = blockIdx.y * 64, n0 = blockIdx.x * 64;
  float acc[4][4] = {};
  for (int kt = 0; kt < K; kt += 16) {
    __syncthreads();
#pragma unroll
    for (int q = 0; q < 4; ++q) {
      int idx = q * 256 + tid;
      int r = idx >> 4, c = idx & 15;
      Xs[r][c] = X[(size_t)(m0 + r) * K + kt + c];
      float w = W[(size_t)(n0 + r) * K + kt + c];
      float4 b = *(const float4*)(Bm + ((n0 + r) << 2));
      w += 4.f * (b.x * Am[kt + c] + b.y * Am[4096 + kt + c] +
                  b.z * Am[8192 + kt + c] + b.w * Am[12288 + kt + c]);
      Ws[r][c] = w;
    }
    __syncthreads();
#pragma unroll
    for (int k = 0; k < 16; ++k) {
      float xv[4], wv[4];
#pragma unroll
      for (int i = 0; i < 4; ++i) xv[i] = Xs[tm * 4 + i][k];
#pragma unroll
      for (int j = 0; j < 4; ++j) wv[j] = Ws[tn * 4 + j][k];
#pragma unroll
      for (int i = 0; i < 4; ++i)
#pragma unroll
        for (int j = 0; j < 4; ++j) acc[i][j] += xv[i] * wv[j];
    }
  }
#pragma unroll
  for (int i = 0; i < 4; ++i)
#pragma unroll
    for (int j = 0; j < 4; ++j)
      C[(size_t)(m0 + tm * 4 + i) * N + n0 + tn * 4 + j] = acc[i][j];
}

extern "C" void kernel_launch(void* const* d_in, const int* in_sizes, int n_in,
                              void* d_out, int out_size, void* d_ws, size_t ws_size,
                              hipStream_t stream) {
  const float* x  = (const float*)d_in[0];
  const float* W  = (const float*)d_in[1];
  const float* lA = (const float*)d_in[2];
  const float* lB = (const float*)d_in[3];
  float* out = (float*)d_out;
  const int K = 4096, N = 4096;
  const int M = in_sizes[0] / K;   // 8192
  const size_t need = ((size_t)M + (size_t)N) * (size_t)K * sizeof(u16);

  if (ws_size >= need && (M % 128) == 0) {
    u16* xb = (u16*)d_ws;
    u16* wb = xb + (size_t)M * K;
    const int n8 = M * (K / 8);
    k_cvt_bf16<<<dim3((n8 + 255) / 256), dim3(256), 0, stream>>>(x, xb, n8);
    const int tw = N * (K / 4);
    k_fold_w<<<dim3(tw / 256), dim3(256), 0, stream>>>(W, lA, lB, wb);
    if ((M % 256) == 0 && (N % 256) == 0 && (K % 32) == 0 && K >= 128) {
      k_gemm8p<<<dim3(N / 256, M / 256), dim3(512), 0, stream>>>(xb, wb, out, M, N, K);
    } else {
      k_gemm_bf16<<<dim3(N / 128, M / 128), dim3(256), 0, stream>>>(xb, wb, out, M, N, K);
    }
  } else {
    k_fallback<<<dim3(N / 64, M / 64), dim3(256), 0, stream>>>(x, W, lA, lB, out, M, N, K);
  }
}